// Round 12
// baseline (222.175 us; speedup 1.0000x reference)
//
#include <hip/hip_runtime.h>
#include <hip/hip_bf16.h>

#define D 128
#define FS_CAP 5120

typedef __bf16 bf16_t;
typedef bf16_t bf16x8 __attribute__((ext_vector_type(8)));
typedef float  f32x4  __attribute__((ext_vector_type(4)));
typedef float  f32x2  __attribute__((ext_vector_type(2)));

__device__ __forceinline__ void atomAddF(float* p, float v) {
    unsafeAtomicAdd(p, v);
}

// pack 8 f32 -> 8 fp8 e4m3 (OCP) in 2 dwords
__device__ __forceinline__ uint2 pack_fp8x8(const float* v) {
    unsigned lo = 0, hi = 0;
    lo = __builtin_amdgcn_cvt_pk_fp8_f32(v[0], v[1], lo, false);
    lo = __builtin_amdgcn_cvt_pk_fp8_f32(v[2], v[3], lo, true);
    hi = __builtin_amdgcn_cvt_pk_fp8_f32(v[4], v[5], hi, false);
    hi = __builtin_amdgcn_cvt_pk_fp8_f32(v[6], v[7], hi, true);
    return make_uint2(lo, hi);
}

// accumulate 8 fp8 (2 dwords) into 8 f32
__device__ __forceinline__ void acc_fp8x8(uint2 w, float* acc) {
    f32x2 a = __builtin_amdgcn_cvt_pk_f32_fp8(w.x, false);
    f32x2 b = __builtin_amdgcn_cvt_pk_f32_fp8(w.x, true);
    f32x2 c = __builtin_amdgcn_cvt_pk_f32_fp8(w.y, false);
    f32x2 d = __builtin_amdgcn_cvt_pk_f32_fp8(w.y, true);
    acc[0] += a[0]; acc[1] += a[1]; acc[2] += b[0]; acc[3] += b[1];
    acc[4] += c[0]; acc[5] += c[1]; acc[6] += d[0]; acc[7] += d[1];
}

// ---- fused: fp32->fp8 staging + column totals + chunked dst histogram ----
// 512 blocks. Each block owns an EXCLUSIVE chunkhist row -> plain stores (no atomics,
// no prior zeroing). 4 consecutive rows form one scatter chunk. Single bcount array.
__global__ __launch_bounds__(256) void cvt_colsum_count_kernel(const float* __restrict__ feat,
                                                               uint2* __restrict__ featq,
                                                               float* __restrict__ total,
                                                               const int* __restrict__ dst,
                                                               int* __restrict__ bcount,
                                                               int* __restrict__ chunkhist,
                                                               long long n8, int nE, int NB,
                                                               int echunkC) {
    __shared__ float red[4][16][8];
    __shared__ int hist[1024];
    int tid = threadIdx.x, lane = tid & 63, w = tid >> 6;
    for (int i = tid; i < NB; i += 256) hist[i] = 0;
    __syncthreads();
    long long G = (long long)gridDim.x * 256;
    float acc[8];
    #pragma unroll
    for (int e = 0; e < 8; ++e) acc[e] = 0.f;
    int c0 = blockIdx.x * echunkC;
    int c1 = c0 + echunkC; if (c1 > nE) c1 = nE;
    long long i = (long long)blockIdx.x * 256 + tid;
    int e = c0 + tid;
    while (i < n8 || e < c1) {
        if (i < n8) {
            const float4 a = *(const float4*)&feat[i * 8];
            const float4 b = *(const float4*)&feat[i * 8 + 4];
            float v[8] = {a.x, a.y, a.z, a.w, b.x, b.y, b.z, b.w};
            featq[i] = pack_fp8x8(v);
            acc[0] += a.x; acc[1] += a.y; acc[2] += a.z; acc[3] += a.w;
            acc[4] += b.x; acc[5] += b.y; acc[6] += b.z; acc[7] += b.w;
        }
        if (e < c1) atomicAdd(&hist[dst[e] >> 8], 1);
        i += G; e += 256;
    }
    #pragma unroll
    for (int k = 0; k < 8; ++k) {
        acc[k] += __shfl_xor(acc[k], 16, 64);
        acc[k] += __shfl_xor(acc[k], 32, 64);
    }
    if (lane < 16) {
        #pragma unroll
        for (int k = 0; k < 8; ++k) red[w][lane][k] = acc[k];
    }
    __syncthreads();
    if (tid < 128) {
        int cb = tid >> 3, k = tid & 7;
        float s = red[0][cb][k] + red[1][cb][k] + red[2][cb][k] + red[3][cb][k];
        atomAddF(&total[cb * 8 + k], s);
    }
    int* ch = chunkhist + (size_t)blockIdx.x * 1024;   // exclusive row: plain stores
    for (int k = tid; k < NB; k += 256) {
        int h = hist[k];
        ch[k] = h;
        if (h) atomicAdd(&bcount[k], h);
    }
}

// 128 blocks x 1024 threads: in-register scan of bcount (thread tid owns bucket tid),
// atomic run reservation via zero-based bcur_rel, dense packed scatter (32-edge runs).
// Block 0 publishes bbase for fill_sort. Per-chunk hist = sum of 4 exclusive cvt rows.
__global__ __launch_bounds__(1024) void bucket_scatter_kernel(const int* __restrict__ src,
                                                              const int* __restrict__ dst,
                                                              const int* __restrict__ bcount,
                                                              int* __restrict__ bcur_rel,
                                                              int* __restrict__ bbase,
                                                              unsigned* __restrict__ packed,
                                                              const int* __restrict__ chunkhist,
                                                              int nE, int NB, int echunkS) {
    __shared__ int ws[16];
    __shared__ int cur[1024];
    int blk = blockIdx.x;
    int tid = threadIdx.x, lane = tid & 63, w = tid >> 6;

    int v = (tid < NB) ? bcount[tid] : 0;
    int x = v;
    #pragma unroll
    for (int off = 1; off < 64; off <<= 1) {
        int y = __shfl_up(x, off, 64);
        if (lane >= off) x += y;
    }
    if (lane == 63) ws[w] = x;
    __syncthreads();
    if (w == 0 && lane < 16) {
        int s = ws[lane];
        #pragma unroll
        for (int off = 1; off < 16; off <<= 1) {
            int y = __shfl_up(s, off, 64);
            if (lane >= off) s += y;
        }
        ws[lane] = s;
    }
    __syncthreads();
    int base = (w == 0) ? 0 : ws[w - 1];
    int excl = base + x - v;

    if (blk == 0) {
        if (tid < NB) bbase[tid] = excl;
        if (tid == 0) bbase[NB] = nE;
    }
    // per-chunk run reservation: chunk hist = sum of this chunk's 4 exclusive cvt rows
    if (tid < NB) {
        const int* ch = chunkhist + (size_t)blk * 4 * 1024;
        int h = ch[tid] + ch[1024 + tid] + ch[2048 + tid] + ch[3072 + tid];
        cur[tid] = h ? (excl + atomicAdd(&bcur_rel[tid], h)) : 0;
    }
    __syncthreads();

    int c0 = blk * echunkS;
    int c1 = c0 + echunkS; if (c1 > nE) c1 = nE;
    for (int i = c0 + tid; i < c1; i += 1024) {
        int t = dst[i];
        int b = t >> 8;
        int off = atomicAdd(&cur[b], 1);
        packed[off] = ((unsigned)(t & 255) << 17) | (unsigned)src[i];
    }
}

// one block per bucket, 1024 threads: full in-LDS counting sort, then STREAMING adj write.
__global__ __launch_bounds__(1024) void fill_sort_kernel(const unsigned* __restrict__ packed,
                                                         const int* __restrict__ bbase,
                                                         int* __restrict__ ptr,
                                                         int* __restrict__ adj,
                                                         int n, int NB, int nE) {
    __shared__ int cnt[256];
    __shared__ int lcur[256];
    __shared__ int wsum[4];
    __shared__ int pbuf[FS_CAP];
    __shared__ int sbuf[FS_CAP];
    int b = blockIdx.x;
    int tid = threadIdx.x, lane = tid & 63, w = tid >> 6;
    int base = bbase[b], end = bbase[b + 1], m = end - base;
    bool fast = (m <= FS_CAP);
    if (tid < 256) cnt[tid] = 0;
    __syncthreads();
    if (fast) {
        for (int i = tid; i < m; i += 1024) {
            int pv = (int)packed[base + i];
            pbuf[i] = pv;
            atomicAdd(&cnt[pv >> 17], 1);
        }
    } else {
        for (int i = tid; i < m; i += 1024)
            atomicAdd(&cnt[packed[base + i] >> 17], 1);
    }
    __syncthreads();
    int v = 0, x = 0;
    if (tid < 256) {
        v = cnt[tid];
        x = v;
        #pragma unroll
        for (int off = 1; off < 64; off <<= 1) {
            int y = __shfl_up(x, off, 64);
            if (lane >= off) x += y;
        }
        if (lane == 63) wsum[w] = x;
    }
    __syncthreads();
    if (tid < 256) {
        int wb = 0;
        for (int k = 0; k < w; ++k) wb += wsum[k];
        int excl = wb + x - v;
        lcur[tid] = fast ? excl : base + excl;
        int node = b * 256 + tid;
        if (node < n) ptr[node] = base + excl;
    }
    if (b == NB - 1 && tid == 0) ptr[n] = nE;
    __syncthreads();
    if (fast) {
        for (int i = tid; i < m; i += 1024) {
            int pv = pbuf[i];
            int j = pv >> 17;
            int pos = atomicAdd(&lcur[j], 1);   // LDS atomic
            sbuf[pos] = pv & 0x1FFFF;
        }
        __syncthreads();
        for (int i = tid; i < m; i += 1024)
            adj[base + i] = sbuf[i];            // coalesced stream
    } else {
        for (int i = tid; i < m; i += 1024) {
            int pv = (int)packed[base + i];
            int j = pv >> 17;
            int pos = atomicAdd(&lcur[j], 1);
            adj[pos] = pv & 0x1FFFF;
        }
    }
}

// ---- fused: CSR gather (fp8 rows, asm 16-deep loads, cross-group pipelined chain)
//      + normalize + MFMA. Processes absolute group range [gbeg, gend). ----
__global__ __launch_bounds__(256, 4) void gather_mfma_kernel(const uint2* __restrict__ featq,
                                                             const int* __restrict__ ptr,
                                                             const int* __restrict__ adj,
                                                             const float* __restrict__ total,
                                                             const float* __restrict__ W,
                                                             const float* __restrict__ bias,
                                                             float* __restrict__ out,
                                                             int n, int gbeg, int gend) {
    __shared__ bf16_t s_hn[2][16][136];

    int tid  = threadIdx.x;
    int lane = tid & 63;
    int w    = tid >> 6;
    int quad = lane >> 4;
    int l16  = lane & 15;

    int n0 = w * 32;
    bf16x8 bfrag[4][2];
    #pragma unroll
    for (int s = 0; s < 4; ++s)
        #pragma unroll
        for (int c = 0; c < 2; ++c) {
            const float* wp = W + (size_t)(n0 + 16 * c + l16) * D + 32 * s + 8 * quad;
            float4 wa = *(const float4*)wp;
            float4 wb = *(const float4*)(wp + 4);
            bf16x8 bf;
            bf[0] = (bf16_t)wa.x; bf[1] = (bf16_t)wa.y; bf[2] = (bf16_t)wa.z; bf[3] = (bf16_t)wa.w;
            bf[4] = (bf16_t)wb.x; bf[5] = (bf16_t)wb.y; bf[6] = (bf16_t)wb.z; bf[7] = (bf16_t)wb.w;
            bfrag[s][c] = bf;
        }
    float bias0 = bias[n0 + l16];
    float bias1 = bias[n0 + 16 + l16];

    int k_node = tid >> 4;
    int d8 = (tid & 15) * 8;
    float tot8[8];
    {
        float4 ta = *(const float4*)&total[d8];
        float4 tb = *(const float4*)&total[d8 + 4];
        tot8[0] = ta.x; tot8[1] = ta.y; tot8[2] = ta.z; tot8[3] = ta.w;
        tot8[4] = tb.x; tot8[5] = tb.y; tot8[6] = tb.z; tot8[7] = tb.w;
    }

    unsigned sliceoff = (unsigned)(tid & 15) * 8;   // byte offset of lane's 8B slice in row
    unsigned long long fbase = (unsigned long long)featq;
    int pb = 0;
    int gstride = gridDim.x;
    int g = gbeg + blockIdx.x;

    // prologue: resolve first group's ptr pair + first adj batch
    int p0 = 0, p1 = 0, madj = 0;
    if (g < gend) {
        int v = g * 16 + k_node;
        if (v < n) { p0 = ptr[v]; p1 = ptr[v + 1]; }
        if (p0 < p1) { int q = p0 + l16; if (q > p1 - 1) q = p1 - 1; madj = adj[q]; }
    }

    for (; g < gend; g += gstride) {
        int gn = g + gstride;
        // prefetch NEXT group's ptr pair; latency hides under this group's row loads
        int np0 = 0, np1 = 0;
        if (gn < gend) {
            int vn = gn * 16 + k_node;
            if (vn < n) { np0 = ptr[vn]; np1 = ptr[vn + 1]; }
        }

        float acc8[8];
        #pragma unroll
        for (int e = 0; e < 8; ++e) acc8[e] = 0.f;

        for (int p = p0; p < p1; p += 16) {
            int rem = p1 - p;
            unsigned voff[16];
            #pragma unroll
            for (int i = 0; i < 16; ++i) {
                int idx = __shfl(madj, (lane & 48) + i, 64);
                voff[i] = ((unsigned)idx << 7) | sliceoff;
            }
            uint2 f[16];
            #pragma unroll
            for (int i = 0; i < 16; ++i)
                asm volatile("global_load_dwordx2 %0, %1, %2"
                             : "=v"(f[i]) : "v"(voff[i]), "s"(fbase));
            // prefetch next batch's adj while rows are in flight
            int adjn = 0, pn = p + 16;
            if (pn < p1) { int q = pn + l16; if (q > p1 - 1) q = p1 - 1; adjn = adj[q]; }
            // counted wait: consume oldest 8 rows while newest 8 still fly
            asm volatile("s_waitcnt vmcnt(8)" ::: "memory");
            __builtin_amdgcn_sched_barrier(0);
            #pragma unroll
            for (int i = 0; i < 8; ++i) if (i < rem) acc_fp8x8(f[i], acc8);
            asm volatile("s_waitcnt vmcnt(0)" ::: "memory");
            __builtin_amdgcn_sched_barrier(0);
            #pragma unroll
            for (int i = 8; i < 16; ++i) if (i < rem) acc_fp8x8(f[i], acc8);
            madj = adjn;
        }

        int v = g * 16 + k_node;
        bool valid = v < n;
        float h8[8], ss = 0.f;
        #pragma unroll
        for (int e = 0; e < 8; ++e) {
            h8[e] = valid ? (tot8[e] - acc8[e]) : 0.f;
            ss = fmaf(h8[e], h8[e], ss);
        }
        ss += __shfl_xor(ss, 1, 64);
        ss += __shfl_xor(ss, 2, 64);
        ss += __shfl_xor(ss, 4, 64);
        ss += __shfl_xor(ss, 8, 64);
        float rinv = 1.0f / fmaxf(sqrtf(ss), 1e-12f);

        bf16x8 hv;
        #pragma unroll
        for (int e = 0; e < 8; ++e) hv[e] = (bf16_t)(h8[e] * rinv);
        *(bf16x8*)&s_hn[pb][k_node][d8] = hv;
        __syncthreads();

        // hand off prefetched ptr pair; issue next group's first adj batch NOW so its
        // latency hides under the MFMA phase below
        p0 = np0; p1 = np1; madj = 0;
        if (p0 < p1) { int q = p0 + l16; if (q > p1 - 1) q = p1 - 1; madj = adj[q]; }

        f32x4 acc0 = {0.f, 0.f, 0.f, 0.f};
        f32x4 acc1 = {0.f, 0.f, 0.f, 0.f};
        #pragma unroll
        for (int s = 0; s < 4; ++s) {
            bf16x8 a = *(const bf16x8*)&s_hn[pb][l16][32 * s + 8 * quad];
            acc0 = __builtin_amdgcn_mfma_f32_16x16x32_bf16(a, bfrag[s][0], acc0, 0, 0, 0);
            acc1 = __builtin_amdgcn_mfma_f32_16x16x32_bf16(a, bfrag[s][1], acc1, 0, 0, 0);
        }
        #pragma unroll
        for (int r = 0; r < 4; ++r) {
            int row = quad * 4 + r;
            int vr = g * 16 + row;
            if (vr < n) {
                out[(size_t)vr * D + n0 + l16]      = acc0[r] + bias0;
                out[(size_t)vr * D + n0 + 16 + l16] = acc1[r] + bias1;
            }
        }
        pb ^= 1;   // double-buffered s_hn: no trailing barrier needed
    }
}

// ---------------- fallback: round-3 atomic scatter path ----------------
__global__ __launch_bounds__(128) void col_sum_kernel(const float* __restrict__ feat,
                                                      float* __restrict__ total, int n) {
    int d = threadIdx.x;
    float acc = 0.f;
    for (int r = blockIdx.x; r < n; r += gridDim.x)
        acc += feat[(size_t)r * D + d];
    atomAddF(&total[d], acc);
}

__global__ __launch_bounds__(256) void scatter_kernel(const float* __restrict__ feat,
                                                      const int* __restrict__ src,
                                                      const int* __restrict__ dst,
                                                      float* __restrict__ neigh, int nE) {
    long long nwork = (long long)nE * 64;
    long long stride = (long long)gridDim.x * 256;
    for (long long i = (long long)blockIdx.x * 256 + threadIdx.x; i < nwork; i += stride) {
        int e = (int)(i >> 6);
        int d2 = (int)(i & 63) * 2;
        int s = src[e], t = dst[e];
        const float2 vv = *(const float2*)&feat[(size_t)s * D + d2];
        float* p = &neigh[(size_t)t * D + d2];
        atomAddF(p + 0, vv.x);
        atomAddF(p + 1, vv.y);
    }
}

__global__ __launch_bounds__(256) void finalize_kernel(const float* __restrict__ neigh,
                                                       const float* __restrict__ total,
                                                       const float* __restrict__ W,
                                                       const float* __restrict__ bias,
                                                       float* __restrict__ out,
                                                       int n, int ngroups) {
    __shared__ __hip_bfloat16 Wt[D * D];
    __shared__ __align__(16) float hnt[2][D][4];
    __shared__ float red[2][2][4];
    int tid = threadIdx.x;
    for (int idx = tid; idx < D * D; idx += 256) {
        int j = idx & 127, dd = idx >> 7;
        Wt[idx] = __float2bfloat16(W[(size_t)j * D + dd]);
    }
    int half = tid >> 7, d = tid & 127, wih = (tid >> 6) & 1, lane = tid & 63;
    float bj = bias[d], tot = total[d];
    __syncthreads();
    for (int g = blockIdx.x; g < ngroups; g += gridDim.x) {
        int nb = g * 8 + half * 4;
        float h0=0,h1=0,h2=0,h3=0;
        if (nb+0 < n) h0 = tot - neigh[(size_t)(nb+0)*D + d];
        if (nb+1 < n) h1 = tot - neigh[(size_t)(nb+1)*D + d];
        if (nb+2 < n) h2 = tot - neigh[(size_t)(nb+2)*D + d];
        if (nb+3 < n) h3 = tot - neigh[(size_t)(nb+3)*D + d];
        float s0=h0*h0,s1=h1*h1,s2=h2*h2,s3=h3*h3;
        #pragma unroll
        for (int off = 32; off > 0; off >>= 1) {
            s0 += __shfl_xor(s0, off, 64); s1 += __shfl_xor(s1, off, 64);
            s2 += __shfl_xor(s2, off, 64); s3 += __shfl_xor(s3, off, 64);
        }
        if (lane == 0) { red[half][wih][0]=s0; red[half][wih][1]=s1; red[half][wih][2]=s2; red[half][wih][3]=s3; }
        __syncthreads();
        float rinv[4];
        #pragma unroll
        for (int k = 0; k < 4; ++k)
            rinv[k] = 1.0f / fmaxf(sqrtf(red[half][0][k] + red[half][1][k]), 1e-12f);
        hnt[half][d][0]=h0*rinv[0]; hnt[half][d][1]=h1*rinv[1];
        hnt[half][d][2]=h2*rinv[2]; hnt[half][d][3]=h3*rinv[3];
        __syncthreads();
        float a0=0,a1=0,a2=0,a3=0;
        #pragma unroll 8
        for (int dd = 0; dd < D; ++dd) {
            float4 hn4 = *(const float4*)&hnt[half][dd][0];
            float wv = __bfloat162float(Wt[dd * D + d]);
            a0 = fmaf(hn4.x, wv, a0); a1 = fmaf(hn4.y, wv, a1);
            a2 = fmaf(hn4.z, wv, a2); a3 = fmaf(hn4.w, wv, a3);
        }
        if (nb+0 < n) out[(size_t)(nb+0)*D + d] = a0 + bj;
        if (nb+1 < n) out[(size_t)(nb+1)*D + d] = a1 + bj;
        if (nb+2 < n) out[(size_t)(nb+2)*D + d] = a2 + bj;
        if (nb+3 < n) out[(size_t)(nb+3)*D + d] = a3 + bj;
        __syncthreads();
    }
}

static inline size_t align_up(size_t x, size_t a) { return (x + a - 1) & ~(a - 1); }

extern "C" void kernel_launch(void* const* d_in, const int* in_sizes, int n_in,
                              void* d_out, int out_size, void* d_ws, size_t ws_size,
                              hipStream_t stream) {
    const float* feat = (const float*)d_in[0];
    const float* W    = (const float*)d_in[1];
    const float* bias = (const float*)d_in[2];
    const int*   src  = (const int*)d_in[3];
    const int*   dst  = (const int*)d_in[4];
    float* out = (float*)d_out;

    int n  = in_sizes[0] / D;   // 100000
    int nE = in_sizes[3];       // 1600000
    int NB = (n + 255) / 256;   // 256-node buckets (391)

    // ws layout: [total 512][bcount 4K][bcur_rel 4K]  <- zeroed region (~8.7 KB)
    //            [chist 2M (store-only)][bbase 4.5K][ptr 4(n+1)][adj 4nE][packed 4nE][featq nD]
    char* wsb = (char*)d_ws;
    size_t o_total  = 0;
    size_t o_bcount = 512;
    size_t o_bcurr  = 512 + 4096;
    size_t o_zend   = o_bcurr + 4096;                      // end of zeroed region
    size_t o_chist  = align_up(o_zend, 512);
    size_t o_bbase  = o_chist + (size_t)512 * 1024 * 4;
    size_t o_ptr    = align_up(o_bbase + 4608, 512);
    size_t o_adj    = align_up(o_ptr + (size_t)4 * (n + 1), 512);
    size_t o_packed = o_adj + (size_t)4 * nE;
    size_t o_featq  = align_up(o_packed + (size_t)4 * nE, 512);
    size_t needNew  = o_featq + (size_t)n * D;

    float*    total  = (float*)(wsb + o_total);
    int*      bcount = (int*)(wsb + o_bcount);
    int*      bcurr  = (int*)(wsb + o_bcurr);
    int*      chist  = (int*)(wsb + o_chist);
    int*      bbase  = (int*)(wsb + o_bbase);
    int*      ptr    = (int*)(wsb + o_ptr);
    int*      adj    = (int*)(wsb + o_adj);
    unsigned* packed = (unsigned*)(wsb + o_packed);
    uint2*    featq  = (uint2*)(wsb + o_featq);

    long long n8 = (long long)n * (D / 8);
    int ngroups16 = (n + 15) / 16;
    int ghalf = ngroups16 / 2;

    bool packOK = (n <= (1 << 17)) && (NB <= 1024);

    if (ws_size >= needNew && packOK) {
        hipMemsetAsync(wsb, 0, o_zend, stream);    // zero total + bcount + bcur_rel only
        int echunkC = (nE + 511) / 512;            // cvt per-block edge chunk
        int echunkS = echunkC * 4;                 // scatter per-block chunk (128 blocks)
        cvt_colsum_count_kernel<<<512, 256, 0, stream>>>(feat, featq, total, dst, bcount,
                                                         chist, n8, nE, NB, echunkC);
        bucket_scatter_kernel<<<128, 1024, 0, stream>>>(src, dst, bcount, bcurr, bbase,
                                                        packed, chist, nE, NB, echunkS);
        fill_sort_kernel<<<NB, 1024, 0, stream>>>(packed, bbase, ptr, adj, n, NB, nE);
        // gather split into two half-range dispatches (~32 us each) so the slowest
        // BUILD kernel surfaces in the rocprof top-5 with full counters.
        if (ghalf > 0) {
            int grid_a = (ghalf + 1) / 2;
            gather_mfma_kernel<<<grid_a, 256, 0, stream>>>(featq, ptr, adj, total, W,
                                                           bias, out, n, 0, ghalf);
        }
        {
            int gb = ngroups16 - ghalf;
            int grid_b = (gb + 1) / 2;
            if (grid_b < 1) grid_b = 1;
            gather_mfma_kernel<<<grid_b, 256, 0, stream>>>(featq, ptr, adj, total, W,
                                                           bias, out, n, ghalf, ngroups16);
        }
    } else {
        float* neigh = out;
        if (ws_size >= D * sizeof(float))
            hipMemsetAsync(d_ws, 0, D * sizeof(float), stream);
        hipMemsetAsync(neigh, 0, (size_t)out_size * sizeof(float), stream);
        col_sum_kernel<<<512, 128, 0, stream>>>(feat, total, n);
        scatter_kernel<<<16384, 256, 0, stream>>>(feat, src, dst, neigh, nE);
        int ngroups = (n + 7) / 8;
        finalize_kernel<<<2048, 256, 0, stream>>>(neigh, total, W, bias, out, n, ngroups);
    }
}

// Round 13
// 206.696 us; speedup vs baseline: 1.0749x; 1.0749x over previous
//
#include <hip/hip_runtime.h>
#include <hip/hip_bf16.h>

#define D 128
#define FS_CAP 5120

typedef __bf16 bf16_t;
typedef bf16_t bf16x8 __attribute__((ext_vector_type(8)));
typedef float  f32x4  __attribute__((ext_vector_type(4)));
typedef float  f32x2  __attribute__((ext_vector_type(2)));

__device__ __forceinline__ void atomAddF(float* p, float v) {
    unsafeAtomicAdd(p, v);
}

// pack 8 f32 -> 8 fp8 e4m3 (OCP) in 2 dwords
__device__ __forceinline__ uint2 pack_fp8x8(const float* v) {
    unsigned lo = 0, hi = 0;
    lo = __builtin_amdgcn_cvt_pk_fp8_f32(v[0], v[1], lo, false);
    lo = __builtin_amdgcn_cvt_pk_fp8_f32(v[2], v[3], lo, true);
    hi = __builtin_amdgcn_cvt_pk_fp8_f32(v[4], v[5], hi, false);
    hi = __builtin_amdgcn_cvt_pk_fp8_f32(v[6], v[7], hi, true);
    return make_uint2(lo, hi);
}

// accumulate 8 fp8 (2 dwords) into 8 f32
__device__ __forceinline__ void acc_fp8x8(uint2 w, float* acc) {
    f32x2 a = __builtin_amdgcn_cvt_pk_f32_fp8(w.x, false);
    f32x2 b = __builtin_amdgcn_cvt_pk_f32_fp8(w.x, true);
    f32x2 c = __builtin_amdgcn_cvt_pk_f32_fp8(w.y, false);
    f32x2 d = __builtin_amdgcn_cvt_pk_f32_fp8(w.y, true);
    acc[0] += a[0]; acc[1] += a[1]; acc[2] += b[0]; acc[3] += b[1];
    acc[4] += c[0]; acc[5] += c[1]; acc[6] += d[0]; acc[7] += d[1];
}

// ---- fused: fp32->fp8 staging + column totals + chunked dst histogram ----
// 512 blocks. Feat stream is 2x-unrolled (rows i and i+G independent -> 4 float4
// loads in flight per wave iteration; attacks the measured MLP starvation:
// R9 showed 745 GB/s @ VALUBusy 2.7%, occupancy 60% = latency-bound).
// Each block owns an EXCLUSIVE chunkhist row (plain stores). 2 rows per scatter chunk.
__global__ __launch_bounds__(256) void cvt_colsum_count_kernel(const float* __restrict__ feat,
                                                               uint2* __restrict__ featq,
                                                               float* __restrict__ total,
                                                               const int* __restrict__ dst,
                                                               int* __restrict__ bcount,
                                                               int* __restrict__ chunkhist,
                                                               long long n8, int nE, int NB,
                                                               int echunkC) {
    __shared__ float red[4][16][8];
    __shared__ int hist[1024];
    int tid = threadIdx.x, lane = tid & 63, w = tid >> 6;
    for (int i = tid; i < NB; i += 256) hist[i] = 0;
    __syncthreads();
    long long G = (long long)gridDim.x * 256;
    long long step = G * 2;
    float acc[8];
    #pragma unroll
    for (int e = 0; e < 8; ++e) acc[e] = 0.f;
    int c0 = blockIdx.x * echunkC;
    int c1 = c0 + echunkC; if (c1 > nE) c1 = nE;
    long long i = (long long)blockIdx.x * 256 + tid;
    int e = c0 + tid;
    while (i < n8 || e < c1) {
        if (i < n8) {
            long long i2 = i + G;
            bool has2 = i2 < n8;
            // issue all 4 independent loads before converting
            const float4 a0 = *(const float4*)&feat[i * 8];
            const float4 b0 = *(const float4*)&feat[i * 8 + 4];
            float4 a1, b1;
            if (has2) {
                a1 = *(const float4*)&feat[i2 * 8];
                b1 = *(const float4*)&feat[i2 * 8 + 4];
            }
            float v0[8] = {a0.x, a0.y, a0.z, a0.w, b0.x, b0.y, b0.z, b0.w};
            featq[i] = pack_fp8x8(v0);
            acc[0] += a0.x; acc[1] += a0.y; acc[2] += a0.z; acc[3] += a0.w;
            acc[4] += b0.x; acc[5] += b0.y; acc[6] += b0.z; acc[7] += b0.w;
            if (has2) {
                float v1[8] = {a1.x, a1.y, a1.z, a1.w, b1.x, b1.y, b1.z, b1.w};
                featq[i2] = pack_fp8x8(v1);
                acc[0] += a1.x; acc[1] += a1.y; acc[2] += a1.z; acc[3] += a1.w;
                acc[4] += b1.x; acc[5] += b1.y; acc[6] += b1.z; acc[7] += b1.w;
            }
        }
        if (e < c1) atomicAdd(&hist[dst[e] >> 8], 1);
        i += step; e += 256;
    }
    #pragma unroll
    for (int k = 0; k < 8; ++k) {
        acc[k] += __shfl_xor(acc[k], 16, 64);
        acc[k] += __shfl_xor(acc[k], 32, 64);
    }
    if (lane < 16) {
        #pragma unroll
        for (int k = 0; k < 8; ++k) red[w][lane][k] = acc[k];
    }
    __syncthreads();
    if (tid < 128) {
        int cb = tid >> 3, k = tid & 7;
        float s = red[0][cb][k] + red[1][cb][k] + red[2][cb][k] + red[3][cb][k];
        atomAddF(&total[cb * 8 + k], s);
    }
    int* ch = chunkhist + (size_t)blockIdx.x * 1024;   // exclusive row: plain stores
    for (int k = tid; k < NB; k += 256) {
        int h = hist[k];
        ch[k] = h;
        if (h) atomicAdd(&bcount[k], h);
    }
}

// 256 blocks x 1024 threads (FULL CU coverage): in-register scan of bcount,
// atomic run reservation via zero-based bcur_rel, dense packed scatter.
// Block 0 publishes bbase for fill_sort. Per-chunk hist = sum of 2 exclusive cvt rows.
__global__ __launch_bounds__(1024) void bucket_scatter_kernel(const int* __restrict__ src,
                                                              const int* __restrict__ dst,
                                                              const int* __restrict__ bcount,
                                                              int* __restrict__ bcur_rel,
                                                              int* __restrict__ bbase,
                                                              unsigned* __restrict__ packed,
                                                              const int* __restrict__ chunkhist,
                                                              int nE, int NB, int echunkS) {
    __shared__ int ws[16];
    __shared__ int cur[1024];
    int blk = blockIdx.x;
    int tid = threadIdx.x, lane = tid & 63, w = tid >> 6;

    int v = (tid < NB) ? bcount[tid] : 0;
    int x = v;
    #pragma unroll
    for (int off = 1; off < 64; off <<= 1) {
        int y = __shfl_up(x, off, 64);
        if (lane >= off) x += y;
    }
    if (lane == 63) ws[w] = x;
    __syncthreads();
    if (w == 0 && lane < 16) {
        int s = ws[lane];
        #pragma unroll
        for (int off = 1; off < 16; off <<= 1) {
            int y = __shfl_up(s, off, 64);
            if (lane >= off) s += y;
        }
        ws[lane] = s;
    }
    __syncthreads();
    int base = (w == 0) ? 0 : ws[w - 1];
    int excl = base + x - v;

    if (blk == 0) {
        if (tid < NB) bbase[tid] = excl;
        if (tid == 0) bbase[NB] = nE;
    }
    // per-chunk run reservation: chunk hist = sum of this chunk's 2 exclusive cvt rows
    if (tid < NB) {
        const int* ch = chunkhist + (size_t)blk * 2 * 1024;
        int h = ch[tid] + ch[1024 + tid];
        cur[tid] = h ? (excl + atomicAdd(&bcur_rel[tid], h)) : 0;
    }
    __syncthreads();

    int c0 = blk * echunkS;
    int c1 = c0 + echunkS; if (c1 > nE) c1 = nE;
    for (int i = c0 + tid; i < c1; i += 1024) {
        int t = dst[i];
        int b = t >> 8;
        int off = atomicAdd(&cur[b], 1);
        packed[off] = ((unsigned)(t & 255) << 17) | (unsigned)src[i];
    }
}

// one block per bucket, 1024 threads: full in-LDS counting sort, then STREAMING adj write.
__global__ __launch_bounds__(1024) void fill_sort_kernel(const unsigned* __restrict__ packed,
                                                         const int* __restrict__ bbase,
                                                         int* __restrict__ ptr,
                                                         int* __restrict__ adj,
                                                         int n, int NB, int nE) {
    __shared__ int cnt[256];
    __shared__ int lcur[256];
    __shared__ int wsum[4];
    __shared__ int pbuf[FS_CAP];
    __shared__ int sbuf[FS_CAP];
    int b = blockIdx.x;
    int tid = threadIdx.x, lane = tid & 63, w = tid >> 6;
    int base = bbase[b], end = bbase[b + 1], m = end - base;
    bool fast = (m <= FS_CAP);
    if (tid < 256) cnt[tid] = 0;
    __syncthreads();
    if (fast) {
        for (int i = tid; i < m; i += 1024) {
            int pv = (int)packed[base + i];
            pbuf[i] = pv;
            atomicAdd(&cnt[pv >> 17], 1);
        }
    } else {
        for (int i = tid; i < m; i += 1024)
            atomicAdd(&cnt[packed[base + i] >> 17], 1);
    }
    __syncthreads();
    int v = 0, x = 0;
    if (tid < 256) {
        v = cnt[tid];
        x = v;
        #pragma unroll
        for (int off = 1; off < 64; off <<= 1) {
            int y = __shfl_up(x, off, 64);
            if (lane >= off) x += y;
        }
        if (lane == 63) wsum[w] = x;
    }
    __syncthreads();
    if (tid < 256) {
        int wb = 0;
        for (int k = 0; k < w; ++k) wb += wsum[k];
        int excl = wb + x - v;
        lcur[tid] = fast ? excl : base + excl;
        int node = b * 256 + tid;
        if (node < n) ptr[node] = base + excl;
    }
    if (b == NB - 1 && tid == 0) ptr[n] = nE;
    __syncthreads();
    if (fast) {
        for (int i = tid; i < m; i += 1024) {
            int pv = pbuf[i];
            int j = pv >> 17;
            int pos = atomicAdd(&lcur[j], 1);   // LDS atomic
            sbuf[pos] = pv & 0x1FFFF;
        }
        __syncthreads();
        for (int i = tid; i < m; i += 1024)
            adj[base + i] = sbuf[i];            // coalesced stream
    } else {
        for (int i = tid; i < m; i += 1024) {
            int pv = (int)packed[base + i];
            int j = pv >> 17;
            int pos = atomicAdd(&lcur[j], 1);
            adj[pos] = pv & 0x1FFFF;
        }
    }
}

// ---- fused: CSR gather (fp8 rows, asm 16-deep loads, cross-group pipelined chain)
//      + normalize + MFMA ----
__global__ __launch_bounds__(256, 4) void gather_mfma_kernel(const uint2* __restrict__ featq,
                                                             const int* __restrict__ ptr,
                                                             const int* __restrict__ adj,
                                                             const float* __restrict__ total,
                                                             const float* __restrict__ W,
                                                             const float* __restrict__ bias,
                                                             float* __restrict__ out,
                                                             int n, int ngroups) {
    __shared__ bf16_t s_hn[2][16][136];

    int tid  = threadIdx.x;
    int lane = tid & 63;
    int w    = tid >> 6;
    int quad = lane >> 4;
    int l16  = lane & 15;

    int n0 = w * 32;
    bf16x8 bfrag[4][2];
    #pragma unroll
    for (int s = 0; s < 4; ++s)
        #pragma unroll
        for (int c = 0; c < 2; ++c) {
            const float* wp = W + (size_t)(n0 + 16 * c + l16) * D + 32 * s + 8 * quad;
            float4 wa = *(const float4*)wp;
            float4 wb = *(const float4*)(wp + 4);
            bf16x8 bf;
            bf[0] = (bf16_t)wa.x; bf[1] = (bf16_t)wa.y; bf[2] = (bf16_t)wa.z; bf[3] = (bf16_t)wa.w;
            bf[4] = (bf16_t)wb.x; bf[5] = (bf16_t)wb.y; bf[6] = (bf16_t)wb.z; bf[7] = (bf16_t)wb.w;
            bfrag[s][c] = bf;
        }
    float bias0 = bias[n0 + l16];
    float bias1 = bias[n0 + 16 + l16];

    int k_node = tid >> 4;
    int d8 = (tid & 15) * 8;
    float tot8[8];
    {
        float4 ta = *(const float4*)&total[d8];
        float4 tb = *(const float4*)&total[d8 + 4];
        tot8[0] = ta.x; tot8[1] = ta.y; tot8[2] = ta.z; tot8[3] = ta.w;
        tot8[4] = tb.x; tot8[5] = tb.y; tot8[6] = tb.z; tot8[7] = tb.w;
    }

    unsigned sliceoff = (unsigned)(tid & 15) * 8;   // byte offset of lane's 8B slice in row
    unsigned long long fbase = (unsigned long long)featq;
    int pb = 0;
    int gstride = gridDim.x;
    int g = blockIdx.x;

    // prologue: resolve first group's ptr pair + first adj batch
    int p0 = 0, p1 = 0, madj = 0;
    if (g < ngroups) {
        int v = g * 16 + k_node;
        if (v < n) { p0 = ptr[v]; p1 = ptr[v + 1]; }
        if (p0 < p1) { int q = p0 + l16; if (q > p1 - 1) q = p1 - 1; madj = adj[q]; }
    }

    for (; g < ngroups; g += gstride) {
        int gn = g + gstride;
        // prefetch NEXT group's ptr pair; latency hides under this group's row loads
        int np0 = 0, np1 = 0;
        if (gn < ngroups) {
            int vn = gn * 16 + k_node;
            if (vn < n) { np0 = ptr[vn]; np1 = ptr[vn + 1]; }
        }

        float acc8[8];
        #pragma unroll
        for (int e = 0; e < 8; ++e) acc8[e] = 0.f;

        for (int p = p0; p < p1; p += 16) {
            int rem = p1 - p;
            unsigned voff[16];
            #pragma unroll
            for (int i = 0; i < 16; ++i) {
                int idx = __shfl(madj, (lane & 48) + i, 64);
                voff[i] = ((unsigned)idx << 7) | sliceoff;
            }
            uint2 f[16];
            #pragma unroll
            for (int i = 0; i < 16; ++i)
                asm volatile("global_load_dwordx2 %0, %1, %2"
                             : "=v"(f[i]) : "v"(voff[i]), "s"(fbase));
            // prefetch next batch's adj while rows are in flight
            int adjn = 0, pn = p + 16;
            if (pn < p1) { int q = pn + l16; if (q > p1 - 1) q = p1 - 1; adjn = adj[q]; }
            // counted wait: consume oldest 8 rows while newest 8 still fly
            asm volatile("s_waitcnt vmcnt(8)" ::: "memory");
            __builtin_amdgcn_sched_barrier(0);
            #pragma unroll
            for (int i = 0; i < 8; ++i) if (i < rem) acc_fp8x8(f[i], acc8);
            asm volatile("s_waitcnt vmcnt(0)" ::: "memory");
            __builtin_amdgcn_sched_barrier(0);
            #pragma unroll
            for (int i = 8; i < 16; ++i) if (i < rem) acc_fp8x8(f[i], acc8);
            madj = adjn;
        }

        int v = g * 16 + k_node;
        bool valid = v < n;
        float h8[8], ss = 0.f;
        #pragma unroll
        for (int e = 0; e < 8; ++e) {
            h8[e] = valid ? (tot8[e] - acc8[e]) : 0.f;
            ss = fmaf(h8[e], h8[e], ss);
        }
        ss += __shfl_xor(ss, 1, 64);
        ss += __shfl_xor(ss, 2, 64);
        ss += __shfl_xor(ss, 4, 64);
        ss += __shfl_xor(ss, 8, 64);
        float rinv = 1.0f / fmaxf(sqrtf(ss), 1e-12f);

        bf16x8 hv;
        #pragma unroll
        for (int e = 0; e < 8; ++e) hv[e] = (bf16_t)(h8[e] * rinv);
        *(bf16x8*)&s_hn[pb][k_node][d8] = hv;
        __syncthreads();

        // hand off prefetched ptr pair; issue next group's first adj batch NOW so its
        // latency hides under the MFMA phase below
        p0 = np0; p1 = np1; madj = 0;
        if (p0 < p1) { int q = p0 + l16; if (q > p1 - 1) q = p1 - 1; madj = adj[q]; }

        f32x4 acc0 = {0.f, 0.f, 0.f, 0.f};
        f32x4 acc1 = {0.f, 0.f, 0.f, 0.f};
        #pragma unroll
        for (int s = 0; s < 4; ++s) {
            bf16x8 a = *(const bf16x8*)&s_hn[pb][l16][32 * s + 8 * quad];
            acc0 = __builtin_amdgcn_mfma_f32_16x16x32_bf16(a, bfrag[s][0], acc0, 0, 0, 0);
            acc1 = __builtin_amdgcn_mfma_f32_16x16x32_bf16(a, bfrag[s][1], acc1, 0, 0, 0);
        }
        #pragma unroll
        for (int r = 0; r < 4; ++r) {
            int row = quad * 4 + r;
            int vr = g * 16 + row;
            if (vr < n) {
                out[(size_t)vr * D + n0 + l16]      = acc0[r] + bias0;
                out[(size_t)vr * D + n0 + 16 + l16] = acc1[r] + bias1;
            }
        }
        pb ^= 1;   // double-buffered s_hn: no trailing barrier needed
    }
}

// ---------------- fallback: round-3 atomic scatter path ----------------
__global__ __launch_bounds__(128) void col_sum_kernel(const float* __restrict__ feat,
                                                      float* __restrict__ total, int n) {
    int d = threadIdx.x;
    float acc = 0.f;
    for (int r = blockIdx.x; r < n; r += gridDim.x)
        acc += feat[(size_t)r * D + d];
    atomAddF(&total[d], acc);
}

__global__ __launch_bounds__(256) void scatter_kernel(const float* __restrict__ feat,
                                                      const int* __restrict__ src,
                                                      const int* __restrict__ dst,
                                                      float* __restrict__ neigh, int nE) {
    long long nwork = (long long)nE * 64;
    long long stride = (long long)gridDim.x * 256;
    for (long long i = (long long)blockIdx.x * 256 + threadIdx.x; i < nwork; i += stride) {
        int e = (int)(i >> 6);
        int d2 = (int)(i & 63) * 2;
        int s = src[e], t = dst[e];
        const float2 vv = *(const float2*)&feat[(size_t)s * D + d2];
        float* p = &neigh[(size_t)t * D + d2];
        atomAddF(p + 0, vv.x);
        atomAddF(p + 1, vv.y);
    }
}

__global__ __launch_bounds__(256) void finalize_kernel(const float* __restrict__ neigh,
                                                       const float* __restrict__ total,
                                                       const float* __restrict__ W,
                                                       const float* __restrict__ bias,
                                                       float* __restrict__ out,
                                                       int n, int ngroups) {
    __shared__ __hip_bfloat16 Wt[D * D];
    __shared__ __align__(16) float hnt[2][D][4];
    __shared__ float red[2][2][4];
    int tid = threadIdx.x;
    for (int idx = tid; idx < D * D; idx += 256) {
        int j = idx & 127, dd = idx >> 7;
        Wt[idx] = __float2bfloat16(W[(size_t)j * D + dd]);
    }
    int half = tid >> 7, d = tid & 127, wih = (tid >> 6) & 1, lane = tid & 63;
    float bj = bias[d], tot = total[d];
    __syncthreads();
    for (int g = blockIdx.x; g < ngroups; g += gridDim.x) {
        int nb = g * 8 + half * 4;
        float h0=0,h1=0,h2=0,h3=0;
        if (nb+0 < n) h0 = tot - neigh[(size_t)(nb+0)*D + d];
        if (nb+1 < n) h1 = tot - neigh[(size_t)(nb+1)*D + d];
        if (nb+2 < n) h2 = tot - neigh[(size_t)(nb+2)*D + d];
        if (nb+3 < n) h3 = tot - neigh[(size_t)(nb+3)*D + d];
        float s0=h0*h0,s1=h1*h1,s2=h2*h2,s3=h3*h3;
        #pragma unroll
        for (int off = 32; off > 0; off >>= 1) {
            s0 += __shfl_xor(s0, off, 64); s1 += __shfl_xor(s1, off, 64);
            s2 += __shfl_xor(s2, off, 64); s3 += __shfl_xor(s3, off, 64);
        }
        if (lane == 0) { red[half][wih][0]=s0; red[half][wih][1]=s1; red[half][wih][2]=s2; red[half][wih][3]=s3; }
        __syncthreads();
        float rinv[4];
        #pragma unroll
        for (int k = 0; k < 4; ++k)
            rinv[k] = 1.0f / fmaxf(sqrtf(red[half][0][k] + red[half][1][k]), 1e-12f);
        hnt[half][d][0]=h0*rinv[0]; hnt[half][d][1]=h1*rinv[1];
        hnt[half][d][2]=h2*rinv[2]; hnt[half][d][3]=h3*rinv[3];
        __syncthreads();
        float a0=0,a1=0,a2=0,a3=0;
        #pragma unroll 8
        for (int dd = 0; dd < D; ++dd) {
            float4 hn4 = *(const float4*)&hnt[half][dd][0];
            float wv = __bfloat162float(Wt[dd * D + d]);
            a0 = fmaf(hn4.x, wv, a0); a1 = fmaf(hn4.y, wv, a1);
            a2 = fmaf(hn4.z, wv, a2); a3 = fmaf(hn4.w, wv, a3);
        }
        if (nb+0 < n) out[(size_t)(nb+0)*D + d] = a0 + bj;
        if (nb+1 < n) out[(size_t)(nb+1)*D + d] = a1 + bj;
        if (nb+2 < n) out[(size_t)(nb+2)*D + d] = a2 + bj;
        if (nb+3 < n) out[(size_t)(nb+3)*D + d] = a3 + bj;
        __syncthreads();
    }
}

static inline size_t align_up(size_t x, size_t a) { return (x + a - 1) & ~(a - 1); }

extern "C" void kernel_launch(void* const* d_in, const int* in_sizes, int n_in,
                              void* d_out, int out_size, void* d_ws, size_t ws_size,
                              hipStream_t stream) {
    const float* feat = (const float*)d_in[0];
    const float* W    = (const float*)d_in[1];
    const float* bias = (const float*)d_in[2];
    const int*   src  = (const int*)d_in[3];
    const int*   dst  = (const int*)d_in[4];
    float* out = (float*)d_out;

    int n  = in_sizes[0] / D;   // 100000
    int nE = in_sizes[3];       // 1600000
    int NB = (n + 255) / 256;   // 256-node buckets (391)

    // ws layout: [total 512][bcount 4K][bcur_rel 4K]  <- zeroed region (~8.7 KB)
    //            [chist 2M (store-only)][bbase 4.5K][ptr 4(n+1)][adj 4nE][packed 4nE][featq nD]
    char* wsb = (char*)d_ws;
    size_t o_total  = 0;
    size_t o_bcount = 512;
    size_t o_bcurr  = 512 + 4096;
    size_t o_zend   = o_bcurr + 4096;                      // end of zeroed region
    size_t o_chist  = align_up(o_zend, 512);
    size_t o_bbase  = o_chist + (size_t)512 * 1024 * 4;
    size_t o_ptr    = align_up(o_bbase + 4608, 512);
    size_t o_adj    = align_up(o_ptr + (size_t)4 * (n + 1), 512);
    size_t o_packed = o_adj + (size_t)4 * nE;
    size_t o_featq  = align_up(o_packed + (size_t)4 * nE, 512);
    size_t needNew  = o_featq + (size_t)n * D;

    float*    total  = (float*)(wsb + o_total);
    int*      bcount = (int*)(wsb + o_bcount);
    int*      bcurr  = (int*)(wsb + o_bcurr);
    int*      chist  = (int*)(wsb + o_chist);
    int*      bbase  = (int*)(wsb + o_bbase);
    int*      ptr    = (int*)(wsb + o_ptr);
    int*      adj    = (int*)(wsb + o_adj);
    unsigned* packed = (unsigned*)(wsb + o_packed);
    uint2*    featq  = (uint2*)(wsb + o_featq);

    long long n8 = (long long)n * (D / 8);
    int ngroups16 = (n + 15) / 16;
    int grid16 = (ngroups16 + 1) / 2;          // 2 groups per block
    if (grid16 > 16384) grid16 = 16384;

    bool packOK = (n <= (1 << 17)) && (NB <= 1024);

    if (ws_size >= needNew && packOK) {
        hipMemsetAsync(wsb, 0, o_zend, stream);    // zero total + bcount + bcur_rel only
        int echunkC = (nE + 511) / 512;            // cvt per-block edge chunk
        int echunkS = echunkC * 2;                 // scatter per-block chunk (256 blocks)
        cvt_colsum_count_kernel<<<512, 256, 0, stream>>>(feat, featq, total, dst, bcount,
                                                         chist, n8, nE, NB, echunkC);
        bucket_scatter_kernel<<<256, 1024, 0, stream>>>(src, dst, bcount, bcurr, bbase,
                                                        packed, chist, nE, NB, echunkS);
        fill_sort_kernel<<<NB, 1024, 0, stream>>>(packed, bbase, ptr, adj, n, NB, nE);
        gather_mfma_kernel<<<grid16, 256, 0, stream>>>(featq, ptr, adj, total, W,
                                                       bias, out, n, ngroups16);
    } else {
        float* neigh = out;
        if (ws_size >= D * sizeof(float))
            hipMemsetAsync(d_ws, 0, D * sizeof(float), stream);
        hipMemsetAsync(neigh, 0, (size_t)out_size * sizeof(float), stream);
        col_sum_kernel<<<512, 128, 0, stream>>>(feat, total, n);
        scatter_kernel<<<16384, 256, 0, stream>>>(feat, src, dst, neigh, nE);
        int ngroups = (n + 7) / 8;
        finalize_kernel<<<2048, 256, 0, stream>>>(neigh, total, W, bias, out, n, ngroups);
    }
}